// Round 9
// baseline (471.217 us; speedup 1.0000x reference)
//
#include <hip/hip_runtime.h>
#include <cstddef>
#include <math.h>

// Problem constants
#define Dn 256
#define Ln 64
#define Kn 64
#define Pn 8
#define Fn 104
#define Cn 500
#define KF 6656          // Kn*Fn
#define TPB 896          // 14 waves = 7 n-tiles x 2 M-halves
#define PSTR 108         // PREV row stride in floats
#define XROWB 512        // X bf16-plane row stride in BYTES (32 chunks of 16B)
#define NQ 1664          // Kn * (Fn/4) quads

typedef __attribute__((ext_vector_type(8))) short bh8;     // 8 bf16 (4 VGPRs) MFMA frag
typedef __attribute__((ext_vector_type(4))) float f32x4;   // MFMA accumulator
typedef __attribute__((ext_vector_type(2))) float f32x2;   // fp32 pair (native vec ops)

__device__ __forceinline__ unsigned short f2bf_rne(float x) {  // RNE f32->bf16 (cold paths)
  unsigned u = __builtin_bit_cast(unsigned, x);
  u = (u + 0x7fffu + ((u >> 16) & 1u)) >> 16;
  return (unsigned short)u;
}
__device__ __forceinline__ float bf2f(unsigned short h) {
  unsigned u = ((unsigned)h) << 16;
  return __builtin_bit_cast(float, u);
}
// Pack bf16(a)|bf16(b)<<16 with RTZ via one v_perm_b32.
__device__ __forceinline__ unsigned pkhi(float a, float b) {
  return __builtin_amdgcn_perm(__builtin_bit_cast(unsigned, b),
                               __builtin_bit_cast(unsigned, a), 0x07060302u);
}
__device__ __forceinline__ float hi_of(float x) {
  return __builtin_bit_cast(float, __builtin_bit_cast(unsigned, x) & 0xffff0000u);
}

// Stage X[k][c0..c0+3] into hi/lo bf16 planes (RTZ split). (c0 & 3) == 0.
// Swizzle: 16B chunk index (c0>>3) XOR'd with (k&7); row stride 512B.
__device__ __forceinline__ void stage_quad(char* XAc, char* XBc, int k, int c0,
                                           float v0, float v1, float v2, float v3) {
  uint2 hv, lv;
  hv.x = pkhi(v0, v1); hv.y = pkhi(v2, v3);
  const float r0 = v0 - hi_of(v0), r1 = v1 - hi_of(v1);
  const float r2 = v2 - hi_of(v2), r3 = v3 - hi_of(v3);
  lv.x = pkhi(r0, r1); lv.y = pkhi(r2, r3);
  const int off = k * XROWB + ((((c0 >> 3) ^ (k & 7)) << 4) | ((c0 & 7) << 1));
  *reinterpret_cast<uint2*>(XAc + off) = hv;
  *reinterpret_cast<uint2*>(XBc + off) = lv;
}

// Load W fragments (hi+lo, RNE) into registers.
// B-frag layout (16x16x32 bf16): lane l holds col=(l&15), k = kt*32 + (l>>4)*8 + v.
__device__ __forceinline__ void load_w_frags(const float* __restrict__ Wg, int Krows,
                                             int col, int e, bh8* Wh, bh8* Wl) {
  #pragma unroll
  for (int kt = 0; kt < 7; ++kt) {
    bh8 h, l;
    #pragma unroll
    for (int v = 0; v < 8; ++v) {
      int k = kt * 32 + e * 8 + v;
      float x = (k < Krows && col < Fn) ? Wg[k * Fn + col] : 0.f;
      unsigned short hh = f2bf_rne(x);
      unsigned short ll = f2bf_rne(x - bf2f(hh));
      h[v] = (short)hh; l[v] = (short)ll;
    }
    Wh[kt] = h; Wl[kt] = l;
  }
}

// 3-term split-bf16 MFMA GEMM over kt in [k0,k1), + relu epilogue.
// Wave = n-tile (col) x M-half mh. acc is local — never live across other phases.
__device__ __forceinline__ void mfma_gemm(const char* XAc, const char* XBc,
                                          const bh8* Wh, const bh8* Wl,
                                          const float* bms, float* PREVs,
                                          int lane, int col, int mh,
                                          int k0, int k1) {
  const int e = lane >> 4;
  const int rb = lane & 15;
  const float bias = (col < Fn) ? bms[col] : 0.f;
  f32x4 acc[2];
  #pragma unroll
  for (int mti = 0; mti < 2; ++mti) { f32x4 b4 = {bias, bias, bias, bias}; acc[mti] = b4; }
  #pragma unroll
  for (int kt = 0; kt < 7; ++kt) {
    if (kt < k0 || kt >= k1) continue;
    #pragma unroll
    for (int mti = 0; mti < 2; ++mti) {
      const int r = (mh * 2 + mti) * 16 + rb;
      const int chunk = (kt * 4 + e) ^ (rb & 7);
      const bh8 ah = *reinterpret_cast<const bh8*>(XAc + r * XROWB + chunk * 16);
      const bh8 al = *reinterpret_cast<const bh8*>(XBc + r * XROWB + chunk * 16);
      acc[mti] = __builtin_amdgcn_mfma_f32_16x16x32_bf16(ah, Wh[kt], acc[mti], 0, 0, 0);
      acc[mti] = __builtin_amdgcn_mfma_f32_16x16x32_bf16(al, Wh[kt], acc[mti], 0, 0, 0);
      acc[mti] = __builtin_amdgcn_mfma_f32_16x16x32_bf16(ah, Wl[kt], acc[mti], 0, 0, 0);
    }
  }
  // C layout: row = mt*16 + (lane>>4)*4 + j, col = lane&15 (+nt*16).
  if (col < Fn) {
    #pragma unroll
    for (int mti = 0; mti < 2; ++mti) {
      #pragma unroll
      for (int j = 0; j < 4; ++j) {
        int r = (mh * 2 + mti) * 16 + e * 4 + j;
        PREVs[r * PSTR + col] = fmaxf(acc[mti][j], 0.f);
      }
    }
  }
}

// Persistent scan kernel: one block per d, l = 0..63 internal.
// NOTE: 14-wave block forces 4 waves/EU -> HW cap 128 total regs/wave
// (arch VGPR + AGPR). W-frags live in AGPRs; A3 must fit in 64 arch VGPRs.
__global__ __launch_bounds__(TPB) void scan_kernel(
    const float* __restrict__ af,     // (D, L, K, F)
    const int*   __restrict__ pidx,   // (D, L-1, K, P)
    const float* __restrict__ W1, const float* __restrict__ b1,
    const float* __restrict__ Wm, const float* __restrict__ bm,
    const float* __restrict__ att_w,
    float* __restrict__ sink)         // (D, F)
{
  extern __shared__ char smem[];
  char*  XAc   = smem;                          // 32768 B  (hi plane, 64 rows x 512B)
  char*  XBc   = smem + 32768;                  // 32768 B  (lo plane)
  float* PREVs = (float*)(smem + 65536);        // 64*108*4 = 27648 B
  float* bms   = (float*)(smem + 65536 + 27648);         // 112 floats
  float* aws   = (float*)(smem + 65536 + 27648 + 448);   // 104 floats (att_w * log2e)
  int*   idxs  = (int*)  (smem + 65536 + 27648 + 448 + 416); // 512 ints (16B aligned)
  // total = 96096 B

  const int t = threadIdx.x;
  const int d = blockIdx.x;
  const int lane = t & 63;
  const int wvi = t >> 6;               // 0..13
  const int nt = wvi % 7;               // n-tile
  const int mh = wvi / 7;               // M-half
  const int e = lane >> 4;
  const int col = nt * 16 + (lane & 15);

  const float*  afd = af + (size_t)d * (Ln * KF);
  const float4* af4 = reinterpret_cast<const float4*>(afd);
  const int*    pid = pidx + (size_t)d * ((Ln - 1) * Kn * Pn);

  bh8 Wh[7], Wl[7];
  float4 pf4[2];
  int ir0 = 0;

  // ---- init: zero both X planes (pad cols stay 0), stage b1, att_w*log2e ----
  for (int i = t; i < 16384; i += TPB) reinterpret_cast<unsigned*>(XAc)[i] = 0u;
  if (t < Fn) { bms[t] = b1[t]; aws[t] = att_w[t] * 1.44269504f; }
  else if (t < 112) bms[t] = 0.f;
  load_w_frags(W1, Fn, col, e, Wh, Wl);
  // stage atoms0 at X cols 0..103
  #pragma unroll
  for (int j = 0; j < 2; ++j) {
    int q = t + j * TPB;
    if (q < NQ) {
      int k = q / 26, fq = (q - k * 26) << 2;
      float4 v = af4[q];
      stage_quad(XAc, XBc, k, fq, v.x, v.y, v.z, v.w);
    }
  }
  __syncthreads();

  // ---- step 0: PREV = relu(atoms0 @ W1 + b1); K=104 -> kt 0..3 ----
  mfma_gemm(XAc, XBc, Wh, Wl, bms, PREVs, lane, col, mh, 0, 4);
  __syncthreads();

  // ---- restage: Wm frags (rows 0..103 = agg <-> X cols 0..103; rows 104..207 =
  //      atoms <-> X cols 104..207), bm, idx block 0, prefetch atoms block 1 ----
  load_w_frags(Wm, 2 * Fn, col, e, Wh, Wl);
  if (t < Fn) bms[t] = bm[t];
  if (t < 512) idxs[t] = pid[t];
  #pragma unroll
  for (int j = 0; j < 2; ++j) {
    int q = t + j * TPB;
    if (q < NQ) pf4[j] = af4[NQ + q];
  }
  __syncthreads();

  // ---- main scan: l = 1..63 ----
  for (int l = 1; l < Ln; ++l) {
    // A1: stage atoms(l) from prefetch regs at X cols 104..207
    #pragma unroll
    for (int j = 0; j < 2; ++j) {
      int q = t + j * TPB;
      if (q < NQ) {
        int k = q / 26, fq = (q - k * 26) << 2;
        float4 v = pf4[j];
        stage_quad(XAc, XBc, k, Fn + fq, v.x, v.y, v.z, v.w);
      }
    }
    // A2: issue prefetches for l+1 (land during A3 + GEMM)
    if (l < 63) {
      const float4* an = af4 + (size_t)(l + 1) * NQ;
      #pragma unroll
      for (int j = 0; j < 2; ++j) {
        int q = t + j * TPB;
        if (q < NQ) pf4[j] = an[q];
      }
      if (t < 512) ir0 = pid[(size_t)l * 512 + t];
    }
    // A3: gather + softmax(P) + aggregate -> X cols 0..103
    for (int q = t; q < NQ; q += TPB) {
      int k = q / 26, fq = (q - k * 26) << 2;
      const float4 w4 = *reinterpret_cast<const float4*>(aws + fq);
      const f32x2 wa01 = {w4.x, w4.y}, wa23 = {w4.z, w4.w};
      const int4 ia = *reinterpret_cast<const int4*>(idxs + (k << 3));
      const int4 ib = *reinterpret_cast<const int4*>(idxs + (k << 3) + 4);
      const int ip[8] = {ia.x, ia.y, ia.z, ia.w, ib.x, ib.y, ib.z, ib.w};
      float4 vvp[8];
      #pragma unroll
      for (int p = 0; p < Pn; ++p)
        vvp[p] = *reinterpret_cast<const float4*>(PREVs + ip[p] * PSTR + fq);
      // per-col max, chained for v_max3 fusion
      float m0 = fmaxf(fmaxf(fmaxf(fmaxf(fmaxf(fmaxf(fmaxf(
          vvp[0].x, vvp[1].x), vvp[2].x), vvp[3].x), vvp[4].x), vvp[5].x), vvp[6].x), vvp[7].x);
      float m1 = fmaxf(fmaxf(fmaxf(fmaxf(fmaxf(fmaxf(fmaxf(
          vvp[0].y, vvp[1].y), vvp[2].y), vvp[3].y), vvp[4].y), vvp[5].y), vvp[6].y), vvp[7].y);
      float m2 = fmaxf(fmaxf(fmaxf(fmaxf(fmaxf(fmaxf(fmaxf(
          vvp[0].z, vvp[1].z), vvp[2].z), vvp[3].z), vvp[4].z), vvp[5].z), vvp[6].z), vvp[7].z);
      float m3 = fmaxf(fmaxf(fmaxf(fmaxf(fmaxf(fmaxf(fmaxf(
          vvp[0].w, vvp[1].w), vvp[2].w), vvp[3].w), vvp[4].w), vvp[5].w), vvp[6].w), vvp[7].w);
      // native float2 vector math (compiler may emit v_pk_*; allocator keeps
      // freedom to split pairs — the R7 asm pairs caused scratch spills)
      const f32x2 nm01 = wa01 * (f32x2){-m0, -m1};
      const f32x2 nm23 = wa23 * (f32x2){-m2, -m3};
      f32x2 es01 = {0.f, 0.f}, es23 = {0.f, 0.f};
      f32x2 ps01 = {0.f, 0.f}, ps23 = {0.f, 0.f};
      #pragma unroll
      for (int p = 0; p < Pn; ++p) {
        const f32x2 v01 = {vvp[p].x, vvp[p].y}, v23 = {vvp[p].z, vvp[p].w};
        const f32x2 a01 = wa01 * v01 + nm01;
        const f32x2 a23 = wa23 * v23 + nm23;
        const f32x2 e01 = {exp2f(a01.x), exp2f(a01.y)};
        const f32x2 e23 = {exp2f(a23.x), exp2f(a23.y)};
        es01 += e01; es23 += e23;
        ps01 += e01 * v01; ps23 += e23 * v23;
      }
      const float ag0 = ps01.x * __builtin_amdgcn_rcpf(es01.x);
      const float ag1 = ps01.y * __builtin_amdgcn_rcpf(es01.y);
      const float ag2 = ps23.x * __builtin_amdgcn_rcpf(es23.x);
      const float ag3 = ps23.y * __builtin_amdgcn_rcpf(es23.y);
      stage_quad(XAc, XBc, k, fq, ag0, ag1, ag2, ag3);
    }
    __syncthreads();

    // Phase B: full 3-term MFMA GEMM + relu epilogue -> PREV; commit idx for l+1
    mfma_gemm(XAc, XBc, Wh, Wl, bms, PREVs, lane, col, mh, 0, 7);
    if (l < 63 && t < 512) idxs[t] = ir0;
    __syncthreads();
  }

  // sink = last[:, K-1]
  if (t < Fn) sink[d * Fn + t] = PREVs[(Kn - 1) * PSTR + t];
}

// Final: DAG softmax over D, pool, project to C.
__global__ __launch_bounds__(512) void final_kernel(
    const float* __restrict__ sink, const float* __restrict__ dag_w,
    const float* __restrict__ Wf, const float* __restrict__ bf,
    float* __restrict__ out)
{
  extern __shared__ char smem[];
  float* ss = (float*)smem;       // 256*104
  float* pooled = ss + Dn * Fn;   // 104
  const int t = threadIdx.x;
  for (int i = t; i < Dn * Fn; i += 512) ss[i] = sink[i];
  __syncthreads();
  if (t < Fn) {
    float wvv = dag_w[t];
    float m = -3.0e38f;
    for (int dd = 0; dd < Dn; ++dd) m = fmaxf(m, wvv * ss[dd * Fn + t]);
    float es = 0.f, ps = 0.f;
    for (int dd = 0; dd < Dn; ++dd) {
      float v = ss[dd * Fn + t];
      float ex = __expf(wvv * v - m);
      es += ex; ps += ex * v;
    }
    pooled[t] = ps / es;
  }
  __syncthreads();
  if (t < Cn) {
    float a = bf[t];
    for (int f = 0; f < Fn; ++f) a = fmaf(pooled[f], Wf[f * Cn + t], a);
    out[t] = a;
  }
}

extern "C" void kernel_launch(void* const* d_in, const int* in_sizes, int n_in,
                              void* d_out, int out_size, void* d_ws, size_t ws_size,
                              hipStream_t stream) {
  const float* af    = (const float*)d_in[0];
  const int*   pidx  = (const int*)  d_in[1];
  const float* W1    = (const float*)d_in[2];
  const float* b1    = (const float*)d_in[3];
  const float* Wm    = (const float*)d_in[4];
  const float* bm    = (const float*)d_in[5];
  const float* att_w = (const float*)d_in[6];
  const float* dag_w = (const float*)d_in[7];
  const float* Wf    = (const float*)d_in[8];
  const float* bf    = (const float*)d_in[9];
  float* out  = (float*)d_out;
  float* sink = (float*)d_ws;      // 256*104 floats

  constexpr size_t SMEM1 = 96096;
  constexpr size_t SMEM2 = (size_t)(Dn * Fn + Fn) * 4;

  (void)hipFuncSetAttribute((const void*)scan_kernel,
                      hipFuncAttributeMaxDynamicSharedMemorySize, (int)SMEM1);
  (void)hipFuncSetAttribute((const void*)final_kernel,
                      hipFuncAttributeMaxDynamicSharedMemorySize, (int)SMEM2);

  scan_kernel<<<Dn, TPB, SMEM1, stream>>>(af, pidx, W1, b1, Wm, bm, att_w, sink);
  final_kernel<<<1, 512, SMEM2, stream>>>(sink, dag_w, Wf, bf, out);
}

// Round 10
// 414.445 us; speedup vs baseline: 1.1370x; 1.1370x over previous
//
#include <hip/hip_runtime.h>
#include <cstddef>
#include <math.h>

// Problem constants
#define Dn 256
#define Ln 64
#define Kn 64
#define Pn 8
#define Fn 104
#define Cn 500
#define KF 6656          // Kn*Fn
#define TPB 896          // 14 waves = 7 n-tiles x 2 M-halves
#define PSTR 108         // PREV row stride in floats
#define XROWB 512        // X bf16-plane row stride in BYTES (32 chunks of 16B)
#define NQ 1664          // Kn * (Fn/4) quads

typedef __attribute__((ext_vector_type(8))) short bh8;     // 8 bf16 (4 VGPRs) MFMA frag
typedef __attribute__((ext_vector_type(4))) float f32x4;   // MFMA accumulator

__device__ __forceinline__ unsigned short f2bf_rne(float x) {  // RNE f32->bf16 (cold paths)
  unsigned u = __builtin_bit_cast(unsigned, x);
  u = (u + 0x7fffu + ((u >> 16) & 1u)) >> 16;
  return (unsigned short)u;
}
__device__ __forceinline__ float bf2f(unsigned short h) {
  unsigned u = ((unsigned)h) << 16;
  return __builtin_bit_cast(float, u);
}
// Pack bf16(a)|bf16(b)<<16 with RTZ via one v_perm_b32.
__device__ __forceinline__ unsigned pkhi(float a, float b) {
  return __builtin_amdgcn_perm(__builtin_bit_cast(unsigned, b),
                               __builtin_bit_cast(unsigned, a), 0x07060302u);
}
__device__ __forceinline__ float hi_of(float x) {
  return __builtin_bit_cast(float, __builtin_bit_cast(unsigned, x) & 0xffff0000u);
}

// Stage X[k][c0..c0+3] into hi/lo bf16 planes (RTZ split). (c0 & 3) == 0.
// Swizzle: 16B chunk index (c0>>3) XOR'd with (k&7); row stride 512B.
__device__ __forceinline__ void stage_quad(char* XAc, char* XBc, int k, int c0,
                                           float v0, float v1, float v2, float v3) {
  uint2 hv, lv;
  hv.x = pkhi(v0, v1); hv.y = pkhi(v2, v3);
  const float r0 = v0 - hi_of(v0), r1 = v1 - hi_of(v1);
  const float r2 = v2 - hi_of(v2), r3 = v3 - hi_of(v3);
  lv.x = pkhi(r0, r1); lv.y = pkhi(r2, r3);
  const int off = k * XROWB + ((((c0 >> 3) ^ (k & 7)) << 4) | ((c0 & 7) << 1));
  *reinterpret_cast<uint2*>(XAc + off) = hv;
  *reinterpret_cast<uint2*>(XBc + off) = lv;
}

// Load W fragments (hi+lo, RNE) into registers.
// B-frag layout (16x16x32 bf16): lane l holds col=(l&15), k = kt*32 + (l>>4)*8 + v.
__device__ __forceinline__ void load_w_frags(const float* __restrict__ Wg, int Krows,
                                             int col, int e, bh8* Wh, bh8* Wl) {
  #pragma unroll
  for (int kt = 0; kt < 7; ++kt) {
    bh8 h, l;
    #pragma unroll
    for (int v = 0; v < 8; ++v) {
      int k = kt * 32 + e * 8 + v;
      float x = (k < Krows && col < Fn) ? Wg[k * Fn + col] : 0.f;
      unsigned short hh = f2bf_rne(x);
      unsigned short ll = f2bf_rne(x - bf2f(hh));
      h[v] = (short)hh; l[v] = (short)ll;
    }
    Wh[kt] = h; Wl[kt] = l;
  }
}

// 3-term split-bf16 MFMA GEMM over kt in [k0,k1), + relu epilogue.
// Wave = n-tile (col) x M-half mh. acc is local — never live across other phases.
__device__ __forceinline__ void mfma_gemm(const char* XAc, const char* XBc,
                                          const bh8* Wh, const bh8* Wl,
                                          const float* bms, float* PREVs,
                                          int lane, int col, int mh,
                                          int k0, int k1) {
  const int e = lane >> 4;
  const int rb = lane & 15;
  const float bias = (col < Fn) ? bms[col] : 0.f;
  f32x4 acc[2];
  #pragma unroll
  for (int mti = 0; mti < 2; ++mti) { f32x4 b4 = {bias, bias, bias, bias}; acc[mti] = b4; }
  #pragma unroll
  for (int kt = 0; kt < 7; ++kt) {
    if (kt < k0 || kt >= k1) continue;
    #pragma unroll
    for (int mti = 0; mti < 2; ++mti) {
      const int r = (mh * 2 + mti) * 16 + rb;
      const int chunk = (kt * 4 + e) ^ (rb & 7);
      const bh8 ah = *reinterpret_cast<const bh8*>(XAc + r * XROWB + chunk * 16);
      const bh8 al = *reinterpret_cast<const bh8*>(XBc + r * XROWB + chunk * 16);
      acc[mti] = __builtin_amdgcn_mfma_f32_16x16x32_bf16(ah, Wh[kt], acc[mti], 0, 0, 0);
      acc[mti] = __builtin_amdgcn_mfma_f32_16x16x32_bf16(al, Wh[kt], acc[mti], 0, 0, 0);
      acc[mti] = __builtin_amdgcn_mfma_f32_16x16x32_bf16(ah, Wl[kt], acc[mti], 0, 0, 0);
    }
  }
  // C layout: row = mt*16 + (lane>>4)*4 + j, col = lane&15 (+nt*16).
  if (col < Fn) {
    #pragma unroll
    for (int mti = 0; mti < 2; ++mti) {
      #pragma unroll
      for (int j = 0; j < 4; ++j) {
        int r = (mh * 2 + mti) * 16 + e * 4 + j;
        PREVs[r * PSTR + col] = fmaxf(acc[mti][j], 0.f);
      }
    }
  }
}

// Persistent scan kernel: one block per d, l = 0..63 internal.
// 14-wave block -> 4 waves/EU -> HW cap 128 total regs/wave (VGPR+AGPR unified).
// W-frags occupy ~64 AGPRs; A3 must fit 64 arch VGPRs -> per-column processing.
__global__ __launch_bounds__(TPB) void scan_kernel(
    const float* __restrict__ af,     // (D, L, K, F)
    const int*   __restrict__ pidx,   // (D, L-1, K, P)
    const float* __restrict__ W1, const float* __restrict__ b1,
    const float* __restrict__ Wm, const float* __restrict__ bm,
    const float* __restrict__ att_w,
    float* __restrict__ sink)         // (D, F)
{
  extern __shared__ char smem[];
  char*  XAc   = smem;                          // 32768 B  (hi plane, 64 rows x 512B)
  char*  XBc   = smem + 32768;                  // 32768 B  (lo plane)
  float* PREVs = (float*)(smem + 65536);        // 64*108*4 = 27648 B
  float* bms   = (float*)(smem + 65536 + 27648);         // 112 floats
  float* aws   = (float*)(smem + 65536 + 27648 + 448);   // 104 floats (att_w * log2e)
  int*   idxs  = (int*)  (smem + 65536 + 27648 + 448 + 416); // 512 ints (16B aligned)
  // total = 96096 B

  const int t = threadIdx.x;
  const int d = blockIdx.x;
  const int lane = t & 63;
  const int wvi = t >> 6;               // 0..13
  const int nt = wvi % 7;               // n-tile
  const int mh = wvi / 7;               // M-half
  const int e = lane >> 4;
  const int col = nt * 16 + (lane & 15);

  const float*  afd = af + (size_t)d * (Ln * KF);
  const float4* af4 = reinterpret_cast<const float4*>(afd);
  const int*    pid = pidx + (size_t)d * ((Ln - 1) * Kn * Pn);

  bh8 Wh[7], Wl[7];
  float4 pf4[2];
  int ir0 = 0;

  // ---- init: zero both X planes (pad cols stay 0), stage b1, att_w*log2e ----
  for (int i = t; i < 16384; i += TPB) reinterpret_cast<unsigned*>(XAc)[i] = 0u;
  if (t < Fn) { bms[t] = b1[t]; aws[t] = att_w[t] * 1.44269504f; }
  else if (t < 112) bms[t] = 0.f;
  load_w_frags(W1, Fn, col, e, Wh, Wl);
  // stage atoms0 at X cols 0..103
  #pragma unroll
  for (int j = 0; j < 2; ++j) {
    int q = t + j * TPB;
    if (q < NQ) {
      int k = q / 26, fq = (q - k * 26) << 2;
      float4 v = af4[q];
      stage_quad(XAc, XBc, k, fq, v.x, v.y, v.z, v.w);
    }
  }
  __syncthreads();

  // ---- step 0: PREV = relu(atoms0 @ W1 + b1); K=104 -> kt 0..3 ----
  mfma_gemm(XAc, XBc, Wh, Wl, bms, PREVs, lane, col, mh, 0, 4);
  __syncthreads();

  // ---- restage: Wm frags (rows 0..103 = agg <-> X cols 0..103; rows 104..207 =
  //      atoms <-> X cols 104..207), bm, idx block 0, prefetch atoms block 1 ----
  load_w_frags(Wm, 2 * Fn, col, e, Wh, Wl);
  if (t < Fn) bms[t] = bm[t];
  if (t < 512) idxs[t] = pid[t];
  #pragma unroll
  for (int j = 0; j < 2; ++j) {
    int q = t + j * TPB;
    if (q < NQ) pf4[j] = af4[NQ + q];
  }
  __syncthreads();

  // ---- main scan: l = 1..63 ----
  for (int l = 1; l < Ln; ++l) {
    // A1: stage atoms(l) from prefetch regs at X cols 104..207
    #pragma unroll
    for (int j = 0; j < 2; ++j) {
      int q = t + j * TPB;
      if (q < NQ) {
        int k = q / 26, fq = (q - k * 26) << 2;
        float4 v = pf4[j];
        stage_quad(XAc, XBc, k, Fn + fq, v.x, v.y, v.z, v.w);
      }
    }
    // A2: issue prefetches for l+1 (land during A3 + GEMM)
    if (l < 63) {
      const float4* an = af4 + (size_t)(l + 1) * NQ;
      #pragma unroll
      for (int j = 0; j < 2; ++j) {
        int q = t + j * TPB;
        if (q < NQ) pf4[j] = an[q];
      }
      if (t < 512) ir0 = pid[(size_t)l * 512 + t];
    }
    // A3: gather + softmax(P) + aggregate -> X cols 0..103
    // Per-column sequential processing (R4-proven spill-free at 64 VGPR).
    for (int q = t; q < NQ; q += TPB) {
      int k = q / 26, fq = (q - k * 26) << 2;
      const float4 w4 = *reinterpret_cast<const float4*>(aws + fq);
      const float wa[4] = {w4.x, w4.y, w4.z, w4.w};
      const int4 ia = *reinterpret_cast<const int4*>(idxs + (k << 3));
      const int4 ib = *reinterpret_cast<const int4*>(idxs + (k << 3) + 4);
      const int ip[8] = {ia.x, ia.y, ia.z, ia.w, ib.x, ib.y, ib.z, ib.w};
      float vv[8][4];
      #pragma unroll
      for (int p = 0; p < Pn; ++p) {
        float4 v4 = *reinterpret_cast<const float4*>(PREVs + ip[p] * PSTR + fq);
        vv[p][0] = v4.x; vv[p][1] = v4.y; vv[p][2] = v4.z; vv[p][3] = v4.w;
      }
      float ag[4];
      #pragma unroll
      for (int c = 0; c < 4; ++c) {
        float vmax = fmaxf(fmaxf(fmaxf(fmaxf(fmaxf(fmaxf(fmaxf(
            vv[0][c], vv[1][c]), vv[2][c]), vv[3][c]), vv[4][c]), vv[5][c]), vv[6][c]), vv[7][c]);
        const float m = wa[c] * vmax;     // att_w >= 0 -> max(wa*v) = wa*max(v)
        float es = 0.f, ps = 0.f;
        #pragma unroll
        for (int p = 0; p < Pn; ++p) {
          float ex = exp2f(fmaf(wa[c], vv[p][c], -m));   // aws pre-scaled by log2e
          es += ex; ps += ex * vv[p][c];
        }
        ag[c] = ps * __builtin_amdgcn_rcpf(es);   // es >= 1
      }
      stage_quad(XAc, XBc, k, fq, ag[0], ag[1], ag[2], ag[3]);
    }
    __syncthreads();

    // Phase B: full 3-term MFMA GEMM + relu epilogue -> PREV; commit idx for l+1
    mfma_gemm(XAc, XBc, Wh, Wl, bms, PREVs, lane, col, mh, 0, 7);
    if (l < 63 && t < 512) idxs[t] = ir0;
    __syncthreads();
  }

  // sink = last[:, K-1]
  if (t < Fn) sink[d * Fn + t] = PREVs[(Kn - 1) * PSTR + t];
}

// Final: DAG softmax over D, pool, project to C.
__global__ __launch_bounds__(512) void final_kernel(
    const float* __restrict__ sink, const float* __restrict__ dag_w,
    const float* __restrict__ Wf, const float* __restrict__ bf,
    float* __restrict__ out)
{
  extern __shared__ char smem[];
  float* ss = (float*)smem;       // 256*104
  float* pooled = ss + Dn * Fn;   // 104
  const int t = threadIdx.x;
  for (int i = t; i < Dn * Fn; i += 512) ss[i] = sink[i];
  __syncthreads();
  if (t < Fn) {
    float wvv = dag_w[t];
    float m = -3.0e38f;
    for (int dd = 0; dd < Dn; ++dd) m = fmaxf(m, wvv * ss[dd * Fn + t]);
    float es = 0.f, ps = 0.f;
    for (int dd = 0; dd < Dn; ++dd) {
      float v = ss[dd * Fn + t];
      float ex = __expf(wvv * v - m);
      es += ex; ps += ex * v;
    }
    pooled[t] = ps / es;
  }
  __syncthreads();
  if (t < Cn) {
    float a = bf[t];
    for (int f = 0; f < Fn; ++f) a = fmaf(pooled[f], Wf[f * Cn + t], a);
    out[t] = a;
  }
}

extern "C" void kernel_launch(void* const* d_in, const int* in_sizes, int n_in,
                              void* d_out, int out_size, void* d_ws, size_t ws_size,
                              hipStream_t stream) {
  const float* af    = (const float*)d_in[0];
  const int*   pidx  = (const int*)  d_in[1];
  const float* W1    = (const float*)d_in[2];
  const float* b1    = (const float*)d_in[3];
  const float* Wm    = (const float*)d_in[4];
  const float* bm    = (const float*)d_in[5];
  const float* att_w = (const float*)d_in[6];
  const float* dag_w = (const float*)d_in[7];
  const float* Wf    = (const float*)d_in[8];
  const float* bf    = (const float*)d_in[9];
  float* out  = (float*)d_out;
  float* sink = (float*)d_ws;      // 256*104 floats

  constexpr size_t SMEM1 = 96096;
  constexpr size_t SMEM2 = (size_t)(Dn * Fn + Fn) * 4;

  (void)hipFuncSetAttribute((const void*)scan_kernel,
                      hipFuncAttributeMaxDynamicSharedMemorySize, (int)SMEM1);
  (void)hipFuncSetAttribute((const void*)final_kernel,
                      hipFuncAttributeMaxDynamicSharedMemorySize, (int)SMEM2);

  scan_kernel<<<Dn, TPB, SMEM1, stream>>>(af, pidx, W1, b1, Wm, bm, att_w, sink);
  final_kernel<<<1, 512, SMEM2, stream>>>(sink, dag_w, Wf, bf, out);
}

// Round 11
// 353.997 us; speedup vs baseline: 1.3311x; 1.1708x over previous
//
#include <hip/hip_runtime.h>
#include <cstddef>
#include <math.h>

// Problem constants
#define Dn 256
#define Ln 64
#define Kn 64
#define Pn 8
#define Fn 104
#define Cn 500
#define KF 6656          // Kn*Fn
#define TPB 896          // 14 waves = 7 n-tiles x 2 M-halves
#define PSTR 108         // PREV row stride in floats
#define XROWB 512        // X bf16-plane row stride in BYTES (32 chunks of 16B)
#define NQ 1664          // Kn * (Fn/4) quads

typedef __attribute__((ext_vector_type(8))) short bh8;     // 8 bf16 (4 VGPRs) MFMA frag
typedef __attribute__((ext_vector_type(4))) float f32x4;   // MFMA accumulator

__device__ __forceinline__ unsigned short f2bf_rne(float x) {  // RNE f32->bf16 (cold paths)
  unsigned u = __builtin_bit_cast(unsigned, x);
  u = (u + 0x7fffu + ((u >> 16) & 1u)) >> 16;
  return (unsigned short)u;
}
__device__ __forceinline__ float bf2f(unsigned short h) {
  unsigned u = ((unsigned)h) << 16;
  return __builtin_bit_cast(float, u);
}
// Pack bf16(a)|bf16(b)<<16 with RTZ via one v_perm_b32.
__device__ __forceinline__ unsigned pkhi(float a, float b) {
  return __builtin_amdgcn_perm(__builtin_bit_cast(unsigned, b),
                               __builtin_bit_cast(unsigned, a), 0x07060302u);
}
__device__ __forceinline__ float hi_of(float x) {
  return __builtin_bit_cast(float, __builtin_bit_cast(unsigned, x) & 0xffff0000u);
}

// Stage X[k][c0..c0+3] into hi/lo bf16 planes (RTZ split). (c0 & 3) == 0.
// Swizzle: 16B chunk index (c0>>3) XOR'd with (k&7); row stride 512B.
__device__ __forceinline__ void stage_quad(char* XAc, char* XBc, int k, int c0,
                                           float v0, float v1, float v2, float v3) {
  uint2 hv, lv;
  hv.x = pkhi(v0, v1); hv.y = pkhi(v2, v3);
  const float r0 = v0 - hi_of(v0), r1 = v1 - hi_of(v1);
  const float r2 = v2 - hi_of(v2), r3 = v3 - hi_of(v3);
  lv.x = pkhi(r0, r1); lv.y = pkhi(r2, r3);
  const int off = k * XROWB + ((((c0 >> 3) ^ (k & 7)) << 4) | ((c0 & 7) << 1));
  *reinterpret_cast<uint2*>(XAc + off) = hv;
  *reinterpret_cast<uint2*>(XBc + off) = lv;
}

// Load W fragments (hi+lo, RNE) into registers.
// B-frag layout (16x16x32 bf16): lane l holds col=(l&15), k = kt*32 + (l>>4)*8 + v.
__device__ __forceinline__ void load_w_frags(const float* __restrict__ Wg, int Krows,
                                             int col, int e, bh8* Wh, bh8* Wl) {
  #pragma unroll
  for (int kt = 0; kt < 7; ++kt) {
    bh8 h, l;
    #pragma unroll
    for (int v = 0; v < 8; ++v) {
      int k = kt * 32 + e * 8 + v;
      float x = (k < Krows && col < Fn) ? Wg[k * Fn + col] : 0.f;
      unsigned short hh = f2bf_rne(x);
      unsigned short ll = f2bf_rne(x - bf2f(hh));
      h[v] = (short)hh; l[v] = (short)ll;
    }
    Wh[kt] = h; Wl[kt] = l;
  }
}

// 3-term split-bf16 MFMA GEMM over kt in [k0,k1), + relu epilogue.
// Wave = n-tile (col) x M-half mh. acc is local — never live across other phases.
__device__ __forceinline__ void mfma_gemm(const char* XAc, const char* XBc,
                                          const bh8* Wh, const bh8* Wl,
                                          const float* bms, float* PREVs,
                                          int lane, int col, int mh,
                                          int k0, int k1) {
  const int e = lane >> 4;
  const int rb = lane & 15;
  const float bias = (col < Fn) ? bms[col] : 0.f;
  f32x4 acc[2];
  #pragma unroll
  for (int mti = 0; mti < 2; ++mti) { f32x4 b4 = {bias, bias, bias, bias}; acc[mti] = b4; }
  #pragma unroll
  for (int kt = 0; kt < 7; ++kt) {
    if (kt < k0 || kt >= k1) continue;
    #pragma unroll
    for (int mti = 0; mti < 2; ++mti) {
      const int r = (mh * 2 + mti) * 16 + rb;
      const int chunk = (kt * 4 + e) ^ (rb & 7);
      const bh8 ah = *reinterpret_cast<const bh8*>(XAc + r * XROWB + chunk * 16);
      const bh8 al = *reinterpret_cast<const bh8*>(XBc + r * XROWB + chunk * 16);
      acc[mti] = __builtin_amdgcn_mfma_f32_16x16x32_bf16(ah, Wh[kt], acc[mti], 0, 0, 0);
      acc[mti] = __builtin_amdgcn_mfma_f32_16x16x32_bf16(al, Wh[kt], acc[mti], 0, 0, 0);
      acc[mti] = __builtin_amdgcn_mfma_f32_16x16x32_bf16(ah, Wl[kt], acc[mti], 0, 0, 0);
    }
  }
  // C layout: row = mt*16 + (lane>>4)*4 + j, col = lane&15 (+nt*16).
  if (col < Fn) {
    #pragma unroll
    for (int mti = 0; mti < 2; ++mti) {
      #pragma unroll
      for (int j = 0; j < 4; ++j) {
        int r = (mh * 2 + mti) * 16 + e * 4 + j;
        PREVs[r * PSTR + col] = fmaxf(acc[mti][j], 0.f);
      }
    }
  }
}

// Persistent scan kernel: one block per d, l = 0..63 internal.
// 14-wave block -> 4 waves/EU -> HW cap 128 total regs/wave (VGPR+AGPR unified).
// W-frags occupy ~64 AGPRs; A3 must fit 64 arch VGPRs -> per-column processing.
__global__ __launch_bounds__(TPB) void scan_kernel(
    const float* __restrict__ af,     // (D, L, K, F)
    const int*   __restrict__ pidx,   // (D, L-1, K, P)
    const float* __restrict__ W1, const float* __restrict__ b1,
    const float* __restrict__ Wm, const float* __restrict__ bm,
    const float* __restrict__ att_w,
    float* __restrict__ sink)         // (D, F)
{
  extern __shared__ char smem[];
  char*  XAc   = smem;                          // 32768 B  (hi plane, 64 rows x 512B)
  char*  XBc   = smem + 32768;                  // 32768 B  (lo plane)
  float* PREVs = (float*)(smem + 65536);        // 64*108*4 = 27648 B
  float* bms   = (float*)(smem + 65536 + 27648);         // 112 floats
  float* aws   = (float*)(smem + 65536 + 27648 + 448);   // 104 floats (raw att_w)
  int*   idxs  = (int*)  (smem + 65536 + 27648 + 448 + 416); // 512 ints (16B aligned)
  // total = 96096 B

  const int t = threadIdx.x;
  const int d = blockIdx.x;
  const int lane = t & 63;
  const int wvi = t >> 6;               // 0..13
  const int nt = wvi % 7;               // n-tile
  const int mh = wvi / 7;               // M-half
  const int e = lane >> 4;
  const int col = nt * 16 + (lane & 15);

  const float*  afd = af + (size_t)d * (Ln * KF);
  const float4* af4 = reinterpret_cast<const float4*>(afd);
  const int*    pid = pidx + (size_t)d * ((Ln - 1) * Kn * Pn);

  bh8 Wh[7], Wl[7];
  float4 pf4[2];
  int ir0 = 0;

  // ---- init: zero both X planes (pad cols stay 0), stage b1, att_w ----
  for (int i = t; i < 16384; i += TPB) reinterpret_cast<unsigned*>(XAc)[i] = 0u;
  if (t < Fn) { bms[t] = b1[t]; aws[t] = att_w[t]; }
  else if (t < 112) bms[t] = 0.f;
  load_w_frags(W1, Fn, col, e, Wh, Wl);
  // stage atoms0 at X cols 0..103
  #pragma unroll
  for (int j = 0; j < 2; ++j) {
    int q = t + j * TPB;
    if (q < NQ) {
      int k = q / 26, fq = (q - k * 26) << 2;
      float4 v = af4[q];
      stage_quad(XAc, XBc, k, fq, v.x, v.y, v.z, v.w);
    }
  }
  __syncthreads();

  // ---- step 0: PREV = relu(atoms0 @ W1 + b1); K=104 -> kt 0..3 ----
  mfma_gemm(XAc, XBc, Wh, Wl, bms, PREVs, lane, col, mh, 0, 4);
  __syncthreads();

  // ---- restage: Wm frags (rows 0..103 = agg <-> X cols 0..103; rows 104..207 =
  //      atoms <-> X cols 104..207), bm, idx block 0, prefetch atoms block 1 ----
  load_w_frags(Wm, 2 * Fn, col, e, Wh, Wl);
  if (t < Fn) bms[t] = bm[t];
  if (t < 512) idxs[t] = pid[t];
  #pragma unroll
  for (int j = 0; j < 2; ++j) {
    int q = t + j * TPB;
    if (q < NQ) pf4[j] = af4[NQ + q];
  }
  __syncthreads();

  // ---- main scan: l = 1..63 ----
  for (int l = 1; l < Ln; ++l) {
    // A1: stage atoms(l) from prefetch regs at X cols 104..207
    #pragma unroll
    for (int j = 0; j < 2; ++j) {
      int q = t + j * TPB;
      if (q < NQ) {
        int k = q / 26, fq = (q - k * 26) << 2;
        float4 v = pf4[j];
        stage_quad(XAc, XBc, k, Fn + fq, v.x, v.y, v.z, v.w);
      }
    }
    // A2: issue prefetches for l+1 (land during A3 + GEMM)
    if (l < 63) {
      const float4* an = af4 + (size_t)(l + 1) * NQ;
      #pragma unroll
      for (int j = 0; j < 2; ++j) {
        int q = t + j * TPB;
        if (q < NQ) pf4[j] = an[q];
      }
      if (t < 512) ir0 = pid[(size_t)l * 512 + t];
    }
    // A3: gather + softmax(P) + aggregate -> X cols 0..103
    // Per-column sequential processing (spill-free at 64 VGPR); __expf native exp.
    for (int q = t; q < NQ; q += TPB) {
      int k = q / 26, fq = (q - k * 26) << 2;
      const float4 w4 = *reinterpret_cast<const float4*>(aws + fq);
      const float wa[4] = {w4.x, w4.y, w4.z, w4.w};
      const int4 ia = *reinterpret_cast<const int4*>(idxs + (k << 3));
      const int4 ib = *reinterpret_cast<const int4*>(idxs + (k << 3) + 4);
      const int ip[8] = {ia.x, ia.y, ia.z, ia.w, ib.x, ib.y, ib.z, ib.w};
      float vv[8][4];
      #pragma unroll
      for (int p = 0; p < Pn; ++p) {
        float4 v4 = *reinterpret_cast<const float4*>(PREVs + ip[p] * PSTR + fq);
        vv[p][0] = v4.x; vv[p][1] = v4.y; vv[p][2] = v4.z; vv[p][3] = v4.w;
      }
      float ag[4];
      #pragma unroll
      for (int c = 0; c < 4; ++c) {
        float vmax = fmaxf(fmaxf(fmaxf(fmaxf(fmaxf(fmaxf(fmaxf(
            vv[0][c], vv[1][c]), vv[2][c]), vv[3][c]), vv[4][c]), vv[5][c]), vv[6][c]), vv[7][c]);
        const float m = wa[c] * vmax;     // att_w >= 0 -> max(wa*v) = wa*max(v)
        float es = 0.f, ps = 0.f;
        #pragma unroll
        for (int p = 0; p < Pn; ++p) {
          float ex = __expf(fmaf(wa[c], vv[p][c], -m));
          es += ex; ps += ex * vv[p][c];
        }
        ag[c] = ps * __builtin_amdgcn_rcpf(es);   // es >= 1
      }
      stage_quad(XAc, XBc, k, fq, ag[0], ag[1], ag[2], ag[3]);
    }
    __syncthreads();

    // Phase B: full 3-term MFMA GEMM + relu epilogue -> PREV; commit idx for l+1
    mfma_gemm(XAc, XBc, Wh, Wl, bms, PREVs, lane, col, mh, 0, 7);
    if (l < 63 && t < 512) idxs[t] = ir0;
    __syncthreads();
  }

  // sink = last[:, K-1]
  if (t < Fn) sink[d * Fn + t] = PREVs[(Kn - 1) * PSTR + t];
}

// Final: DAG softmax over D, pool, project to C.
__global__ __launch_bounds__(512) void final_kernel(
    const float* __restrict__ sink, const float* __restrict__ dag_w,
    const float* __restrict__ Wf, const float* __restrict__ bf,
    float* __restrict__ out)
{
  extern __shared__ char smem[];
  float* ss = (float*)smem;       // 256*104
  float* pooled = ss + Dn * Fn;   // 104
  const int t = threadIdx.x;
  for (int i = t; i < Dn * Fn; i += 512) ss[i] = sink[i];
  __syncthreads();
  if (t < Fn) {
    float wvv = dag_w[t];
    float m = -3.0e38f;
    for (int dd = 0; dd < Dn; ++dd) m = fmaxf(m, wvv * ss[dd * Fn + t]);
    float es = 0.f, ps = 0.f;
    for (int dd = 0; dd < Dn; ++dd) {
      float v = ss[dd * Fn + t];
      float ex = __expf(wvv * v - m);
      es += ex; ps += ex * v;
    }
    pooled[t] = ps / es;
  }
  __syncthreads();
  if (t < Cn) {
    float a = bf[t];
    for (int f = 0; f < Fn; ++f) a = fmaf(pooled[f], Wf[f * Cn + t], a);
    out[t] = a;
  }
}

extern "C" void kernel_launch(void* const* d_in, const int* in_sizes, int n_in,
                              void* d_out, int out_size, void* d_ws, size_t ws_size,
                              hipStream_t stream) {
  const float* af    = (const float*)d_in[0];
  const int*   pidx  = (const int*)  d_in[1];
  const float* W1    = (const float*)d_in[2];
  const float* b1    = (const float*)d_in[3];
  const float* Wm    = (const float*)d_in[4];
  const float* bm    = (const float*)d_in[5];
  const float* att_w = (const float*)d_in[6];
  const float* dag_w = (const float*)d_in[7];
  const float* Wf    = (const float*)d_in[8];
  const float* bf    = (const float*)d_in[9];
  float* out  = (float*)d_out;
  float* sink = (float*)d_ws;      // 256*104 floats

  constexpr size_t SMEM1 = 96096;
  constexpr size_t SMEM2 = (size_t)(Dn * Fn + Fn) * 4;

  (void)hipFuncSetAttribute((const void*)scan_kernel,
                      hipFuncAttributeMaxDynamicSharedMemorySize, (int)SMEM1);
  (void)hipFuncSetAttribute((const void*)final_kernel,
                      hipFuncAttributeMaxDynamicSharedMemorySize, (int)SMEM2);

  scan_kernel<<<Dn, TPB, SMEM1, stream>>>(af, pidx, W1, b1, Wm, bm, att_w, sink);
  final_kernel<<<1, 512, SMEM2, stream>>>(sink, dag_w, Wf, bf, out);
}